// Round 1
// 177.503 us; speedup vs baseline: 1.1439x; 1.1439x over previous
//
#include <hip/hip_runtime.h>
#include <cstdint>

typedef unsigned long long u64;
typedef unsigned int u32;

#define B_ 4
#define N_ 3600
#define C_ 16
#define NW_ 57        // ceil(N/64) words of adjacency/valid bitmask
#define NPAD_ 3648    // NW_*64
#define RPW_ 4        // rows per wave (k_adj)
#define RPB_ 16       // rows per block (k_adj, 4 waves)
#define HW0_ 1856     // j-half 0: words 0..28  (29 words)
#define HW1_ 1792     // j-half 1: words 29..56 (28 words)
#define CH_ 64        // greedy chunk size (candidates per resolution round)
#define NT_ 512       // threads in fused sort+greedy kernel
#define NWV_ 8        // waves in fused kernel
#define RPWG_ 8       // rows per wave in greedy phases (CH_/NWV_)

// ---------------------------------------------------------------------------
// K1: adjacency bitmask. 4 rows/wave, 16 rows/block; j-range staged in LDS in
// two halves. Lane t holds row word t in a register -> one contiguous store
// per row (57 words).
//
// Exact division-free IoU test:
//   round_f32(inter/denom) >= 0.4f  <=>  inter > (0.4f - 2^-26)*denom in f64
//   (26x24-bit mantissa product is exact; midpoint ties round-to-even to
//   prev(0.4f) < 0.4f -> false, matching strict '>'). denom==0 => inter==0
//   => false, matching 0/0=NaN >= 0.4 false. Zero-padded boxes => false.
// ---------------------------------------------------------------------------
__global__ __launch_bounds__(256, 5) void k_adj(const float* __restrict__ boxes,
                                                u64* __restrict__ adj) {
#pragma clang fp contract(off)
    __shared__ float4 sbox[HW0_];    // (x1,y1,x2,y2), one j-half at a time
    const int tid  = threadIdx.x;
    const int lane = tid & 63;
    const int wv   = tid >> 6;
    const int g    = blockIdx.x;                 // 0 .. B*N/16-1
    const int b    = g / (N_ / RPB_);
    const int r0   = (g % (N_ / RPB_)) * RPB_ + wv * RPW_;
    const size_t bN = (size_t)b * N_;

    float4 bi[RPW_];
    float  ai[RPW_];
#pragma unroll
    for (int r = 0; r < RPW_; ++r) {
        const float4 bx = reinterpret_cast<const float4*>(boxes)[bN + r0 + r];
        const float x1 = bx.x - bx.z * 0.5f;   // cx - w/2 (reference op order)
        const float y1 = bx.y - bx.w * 0.5f;
        const float x2 = x1 + bx.z;
        const float y2 = y1 + bx.w;
        bi[r] = make_float4(x1, y1, x2, y2);
        ai[r] = (x2 - x1) * (y2 - y1);
    }
    const double MID = (double)0.4f - 0x1p-26;   // exact

    u64 row[RPW_];
#pragma unroll
    for (int r = 0; r < RPW_; ++r) row[r] = 0ull;

    int jbase = 0;
    for (int h = 0; h < 2; ++h) {
        const int cnt = h ? HW1_ : HW0_;
        __syncthreads();                         // protect previous half's reads
        for (int jj = tid; jj < cnt; jj += 256) {
            const int j = jbase + jj;
            float x1 = 0.f, y1 = 0.f, x2 = 0.f, y2 = 0.f;
            if (j < N_) {
                const float4 bx = reinterpret_cast<const float4*>(boxes)[bN + j];
                x1 = bx.x - bx.z * 0.5f;
                y1 = bx.y - bx.w * 0.5f;
                x2 = x1 + bx.z;
                y2 = y1 + bx.w;
            }
            sbox[jj] = make_float4(x1, y1, x2, y2);
        }
        __syncthreads();

        const int twn = cnt >> 6;
        for (int tw = 0; tw < twn; ++tw) {
            const int tglob = (jbase >> 6) + tw;
            const int j     = jbase + tw * 64 + lane;
            const float4 bj = sbox[tw * 64 + lane];
            const float ajr = (bj.z - bj.x) * (bj.w - bj.y);
#pragma unroll
            for (int r = 0; r < RPW_; ++r) {
                const float ltx = fmaxf(bi[r].x, bj.x);
                const float lty = fmaxf(bi[r].y, bj.y);
                const float rbx = fminf(bi[r].z, bj.z);
                const float rby = fminf(bi[r].w, bj.w);
                const float whx = fmaxf(rbx - ltx, 0.0f);
                const float why = fmaxf(rby - lty, 0.0f);
                const float inter = whx * why;
                const float denom = (ai[r] + ajr) - inter;
                const int pred = ((double)inter > MID * (double)denom) && (j != r0 + r);
                const u64 m = __ballot(pred);
                if (lane == tglob) row[r] = m;   // 2x v_cndmask
            }
        }
        jbase += cnt;
    }

#pragma unroll
    for (int r = 0; r < RPW_; ++r)
        if (lane < NW_) adj[(bN + r0 + r) * (size_t)NW_ + lane] = row[r];
}

// ---------------------------------------------------------------------------
// K1b: sparse threshold kernel. One wave per row: lane w iterates its adj
// word's set bits, gathers con[j][0..15], fmax-accumulates; 6-step shuffle
// max-reduce; then thr[i][c] = max(adj_con, con_i) (exact: p>=a && p>=b
// <=> p >= fmax(a,b) for non-NaN inputs; adj_con init 0 matches reference
// where(adj, con, 0) and subsumes p>=0).
// ---------------------------------------------------------------------------
__global__ __launch_bounds__(256) void k_acon(const u64* __restrict__ adj,
                                              const float* __restrict__ con,
                                              float* __restrict__ thr) {
    const int tid  = threadIdx.x;
    const int lane = tid & 63;
    const int wv   = tid >> 6;
    const int g    = blockIdx.x;                 // 0 .. B*N/4-1
    const int b    = g / (N_ / 4);
    const int i    = (g % (N_ / 4)) * 4 + wv;
    const size_t bN = (size_t)b * N_;

    u64 w = (lane < NW_) ? adj[(bN + i) * (size_t)NW_ + lane] : 0ull;

    float cm[C_];
#pragma unroll
    for (int k = 0; k < C_; ++k) cm[k] = 0.0f;

    while (w) {
        const int bit = __builtin_ctzll(w); w &= w - 1;
        const int j   = lane * 64 + bit;
        const float4* cp = reinterpret_cast<const float4*>(con + (bN + j) * C_);
        const float4 c0 = cp[0], c1 = cp[1], c2 = cp[2], c3 = cp[3];
        cm[0]  = fmaxf(cm[0],  c0.x); cm[1]  = fmaxf(cm[1],  c0.y);
        cm[2]  = fmaxf(cm[2],  c0.z); cm[3]  = fmaxf(cm[3],  c0.w);
        cm[4]  = fmaxf(cm[4],  c1.x); cm[5]  = fmaxf(cm[5],  c1.y);
        cm[6]  = fmaxf(cm[6],  c1.z); cm[7]  = fmaxf(cm[7],  c1.w);
        cm[8]  = fmaxf(cm[8],  c2.x); cm[9]  = fmaxf(cm[9],  c2.y);
        cm[10] = fmaxf(cm[10], c2.z); cm[11] = fmaxf(cm[11], c2.w);
        cm[12] = fmaxf(cm[12], c3.x); cm[13] = fmaxf(cm[13], c3.y);
        cm[14] = fmaxf(cm[14], c3.z); cm[15] = fmaxf(cm[15], c3.w);
    }

#pragma unroll
    for (int off = 1; off < 64; off <<= 1) {
#pragma unroll
        for (int k = 0; k < C_; ++k) cm[k] = fmaxf(cm[k], __shfl_xor(cm[k], off));
    }
    if (lane == 0) {
        const float4* cp = reinterpret_cast<const float4*>(con + (bN + i) * C_);
        const float4 c0 = cp[0], c1 = cp[1], c2 = cp[2], c3 = cp[3];
        float4* o = reinterpret_cast<float4*>(thr + (bN + i) * C_);
        o[0] = make_float4(fmaxf(cm[0],  c0.x), fmaxf(cm[1],  c0.y),
                           fmaxf(cm[2],  c0.z), fmaxf(cm[3],  c0.w));
        o[1] = make_float4(fmaxf(cm[4],  c1.x), fmaxf(cm[5],  c1.y),
                           fmaxf(cm[6],  c1.z), fmaxf(cm[7],  c1.w));
        o[2] = make_float4(fmaxf(cm[8],  c2.x), fmaxf(cm[9],  c2.y),
                           fmaxf(cm[10], c2.z), fmaxf(cm[11], c2.w));
        o[3] = make_float4(fmaxf(cm[12], c3.x), fmaxf(cm[13], c3.y),
                           fmaxf(cm[14], c3.z), fmaxf(cm[15], c3.w));
    }
}

// ---------------------------------------------------------------------------
// K2 (fused k_prep + k_greedy): one 512-thread block per (b,c).
//  Phase 0: valid0 + vmask ballots (straight into LDS) + compaction into
//           64-bit keys ((~score_bits << 32) | idx -> asc sort == score desc,
//           idx asc, i.e. stable argsort(-scores)).
//  Phase 1: bitonic sort of keys in LDS (8 waves -> half the per-step work
//           of the old 256-thread k_prep; no global round-trip).
//  Phase 2: chunk-parallel greedy (identical algorithm to previous k_greedy,
//           but 8 rows/wave in phases A/C instead of 16). keys[] is dead
//           after the sort, so srows overlays it (union) — LDS unchanged.
// Exactness: candidate accepted iff valid at its turn under prior chunks'
// suppressions (vmask) and earlier accepted rows in-chunk (intra) — the
// reference greedy restricted to valid0 members. Survivor order == greedy
// order == reference output order; suppressed rows stay exact zeros.
// ---------------------------------------------------------------------------
union OvT {
    u64 keys[4096];                 // 32 KB  (live: phase 0/1)
    u64 srows[2][CH_][NW_];         // 58.4 KB (live: phase 2)
};

__global__ __launch_bounds__(NT_) void k_nms(const float* __restrict__ pro,
                                             const float* __restrict__ thr,
                                             const float* __restrict__ conf,
                                             const u64* __restrict__ adj,
                                             const float* __restrict__ boxes,
                                             const float* __restrict__ scales,
                                             float* __restrict__ out) {
#pragma clang fp contract(off)
    __shared__ OvT ov;
    __shared__ u32 sidx[NPAD_];
    __shared__ u64 sintra[CH_];
    __shared__ u64 vmask[NW_];
    __shared__ u64 s_accept;
    __shared__ u32 slist[NPAD_];
    __shared__ u32 s_T;
    __shared__ u32 s_S;
    const int tid  = threadIdx.x;
    const int lane = tid & 63;
    const int wv   = tid >> 6;
    const int bc   = blockIdx.x;
    const int b    = bc / C_, c = bc % C_;
    const size_t bN = (size_t)b * N_;
    const float cf = conf[c];

    if (tid == 0) s_T = 0;
    __syncthreads();

    // --- phase 0: valid0 + vmask + compaction ---
    for (int t = wv; t < NW_; t += NWV_) {
        const int i = t * 64 + lane;
        int pred = 0;
        u32 pk = 0;
        if (i < N_) {
            const size_t off = (bN + i) * C_ + c;
            const float p = pro[off];
            pred = (p >= cf) && (p >= thr[off]);
            const u32 pb = __float_as_uint(p);
            pk = pb ^ ((pb >> 31) ? 0xFFFFFFFFu : 0x80000000u);
        }
        const u64 bm = __ballot(pred);
        if (lane == 0) vmask[t] = bm;
        u32 base = 0;
        if (lane == 0 && bm) base = atomicAdd(&s_T, (u32)__popcll(bm));
        base = (u32)__shfl((int)base, 0);
        if (pred) ov.keys[base + (u32)__popcll(bm & ((1ull << lane) - 1ull))] =
            (((u64)(~pk)) << 32) | (u32)i;
    }
    __syncthreads();

    // --- phase 1: bitonic sort (asc) ---
    const int T = (int)s_T;
    int P = 2;
    while (P < T) P <<= 1;               // P <= 4096
    for (int x = T + tid; x < P; x += NT_) ov.keys[x] = ~0ull;
    __syncthreads();

    for (int k = 2; k <= P; k <<= 1) {
        for (int j = k >> 1; j > 0; j >>= 1) {
            for (int t = tid; t < P; t += NT_) {
                const int ixj = t ^ j;
                if (ixj > t) {
                    const u64 a = ov.keys[t], bb = ov.keys[ixj];
                    const bool up = ((t & k) == 0);
                    if ((a > bb) == up) { ov.keys[t] = bb; ov.keys[ixj] = a; }
                }
            }
            __syncthreads();
        }
    }

    for (int x = tid; x < T; x += NT_) sidx[x] = (u32)(ov.keys[x] & 0xFFFFFFFFull);
    __syncthreads();                     // keys dead; srows may overlay now

    // --- phase 2: chunk-parallel greedy ---
    // stage chunk 0
#pragma unroll
    for (int rr = 0; rr < RPWG_; ++rr) {
        const int r = wv * RPWG_ + rr;
        const u32 idx = (r < T) ? sidx[r] : 0u;
        if (lane < NW_) ov.srows[0][r][lane] = adj[(bN + idx) * (size_t)NW_ + lane];
    }
    __syncthreads();

    u32 S = 0;                           // meaningful in wave 0
    const int NCH = (T + CH_ - 1) / CH_;
    for (int ch = 0; ch < NCH; ++ch) {
        const int cur = ch & 1, nxt = cur ^ 1;
        const int c0 = ch * CH_;
        const int cn = min(CH_, T - c0);
        const int havenext = (ch + 1 < NCH);

        // --- A: prefetch next chunk rows + intra-chunk masks (symmetry) ---
        u64 pre[RPWG_];
#pragma unroll
        for (int rr = 0; rr < RPWG_; ++rr) {
            const int r = wv * RPWG_ + rr;
            const int q = c0 + CH_ + r;
            const u32 idxn = (havenext && q < T) ? sidx[q] : 0u;
            pre[rr] = (havenext && lane < NW_)
                        ? adj[(bN + idxn) * (size_t)NW_ + lane] : 0ull;
        }
#pragma unroll
        for (int rr = 0; rr < RPWG_; ++rr) {
            const int r = wv * RPWG_ + rr;
            const u32 idxr = (c0 + r < T) ? sidx[c0 + r] : 0u;   // uniform/iter
            const u64 rj = ov.srows[cur][lane][idxr >> 6];  // own row, sym.
            const u64 ib = __ballot((lane < cn) && ((rj >> (idxr & 63)) & 1ull));
            if (lane == 0) sintra[r] = ib;
        }
        __syncthreads();

        // --- B: wave 0 sparse resolve + survivor emit ---
        if (wv == 0) {
            const u32 idxme = (c0 + lane < T) ? sidx[c0 + lane] : 0u;
            const u64 vm = vmask[idxme >> 6];            // LDS scatter read
            u64 cv = __ballot((lane < cn) && ((vm >> (idxme & 63)) & 1ull));
            const u64 iv = sintra[lane];
            const u32 ivLo = (u32)iv, ivHi = (u32)(iv >> 32);
            u64 accept = 0ull;
            while (cv) {
                const int r = __builtin_ctzll(cv);
                accept |= 1ull << r;
                const u64 ir =
                    ((u64)(u32)__builtin_amdgcn_readlane((int)ivHi, r) << 32)
                  |  (u64)(u32)__builtin_amdgcn_readlane((int)ivLo, r);
                cv &= ~(ir | (1ull << r));
            }
            if (lane == 0) s_accept = accept;
            const u32 bitl = (u32)((accept >> lane) & 1ull);
            if (bitl) {
                const u32 pos = S + (u32)__popcll(accept & ((1ull << lane) - 1ull));
                slist[pos] = idxme;
            }
            S += (u32)__popcll(accept);
        }
        __syncthreads();

        // --- C: parallel apply + store prefetched rows ---
        const u64 ac = s_accept;
        u64 acc = 0ull;
#pragma unroll
        for (int rr = 0; rr < RPWG_; ++rr) {
            const int r = wv * RPWG_ + rr;
            if ((ac >> r) & 1ull)                        // wave-uniform branch
                acc |= ov.srows[cur][r][min(lane, NW_ - 1)];
        }
        if (lane < NW_ && acc)
            atomicAnd(&vmask[lane], ~acc);
        if (havenext) {
#pragma unroll
            for (int rr = 0; rr < RPWG_; ++rr) {
                const int r = wv * RPWG_ + rr;
                if (lane < NW_) ov.srows[nxt][r][lane] = pre[rr];
            }
        }
        __syncthreads();
    }
    if (wv == 0 && lane == 0) s_S = S;
    __syncthreads();

    // output survivors in greedy order (suppressed rows stay exact zeros)
    const int Sf = (int)s_S;
    const float s = scales[b];
    for (int r = tid; r < Sf; r += NT_) {
        const int idx = (int)slist[r];
        const float4 bx = reinterpret_cast<const float4*>(boxes)[bN + idx];
        const float scx = bx.x * s, scy = bx.y * s, sw = bx.z * s, sh = bx.w * s;
        float* o = out + ((size_t)bc * N_ + r) * 5;
        o[0] = scx - 0.5f * sw;
        o[1] = scy - 0.5f * sh;
        o[2] = scx + 0.5f * sw;
        o[3] = scy + 0.5f * sh;
        o[4] = pro[(bN + idx) * C_ + c];
        out[(size_t)B_ * C_ * N_ * 5 + (size_t)bc * N_ + r] = 1.0f;
    }
}

// ---------------------------------------------------------------------------
extern "C" void kernel_launch(void* const* d_in, const int* in_sizes, int n_in,
                              void* d_out, int out_size, void* d_ws, size_t ws_size,
                              hipStream_t stream) {
    const float* pro    = (const float*)d_in[0];   // (B,N,C)
    const float* con    = (const float*)d_in[1];   // (B,N,C)
    const float* boxes  = (const float*)d_in[2];   // (B,N,4)
    const float* scales = (const float*)d_in[3];   // (B,)
    const float* conf   = (const float*)d_in[4];   // (C,)

    char* ws = (char*)d_ws;
    u64* adj = (u64*)ws;                                   // B*N*NW u64  (6.57 MB)
    size_t off = (size_t)B_ * N_ * NW_ * sizeof(u64);
    float* thr = (float*)(ws + off);                       // B*N*C f32   (0.92 MB)

    hipMemsetAsync(d_out, 0, (size_t)out_size * sizeof(float), stream);
    k_adj <<<B_ * N_ / RPB_, 256, 0, stream>>>(boxes, adj);
    k_acon<<<B_ * N_ / 4,    256, 0, stream>>>(adj, con, thr);
    k_nms <<<B_ * C_,        NT_, 0, stream>>>(pro, thr, conf, adj, boxes,
                                               scales, (float*)d_out);
}

// Round 2
// 173.736 us; speedup vs baseline: 1.1687x; 1.0217x over previous
//
#include <hip/hip_runtime.h>
#include <cstdint>

typedef unsigned long long u64;
typedef unsigned int u32;

#define B_ 4
#define N_ 3600
#define C_ 16
#define NW_ 57        // ceil(N/64) words of adjacency/valid bitmask
#define NPAD_ 3648    // NW_*64
#define RPW_ 4        // rows per wave (k_adj)
#define RPB_ 16       // rows per block (k_adj, 4 waves)
#define HW0_ 1856     // j-half 0: words 0..28  (29 words)
#define HW1_ 1792     // j-half 1: words 29..56 (28 words)
#define CH_ 64        // greedy chunk size (candidates per resolution round)
#define NT_ 512       // threads in fused sort+greedy kernel
#define NWV_ 8        // waves in fused kernel
#define RPWG_ 8       // rows per wave in greedy phases (CH_/NWV_)

// ---------------------------------------------------------------------------
// K1 (fused adjacency + k_acon): 4 rows/wave, 16 rows/block; j-range staged
// in LDS in two halves. Lane t holds row word t in a register -> one
// contiguous store per row (57 words).
//
// Exact division-free IoU test:
//   round_f32(inter/denom) >= 0.4f  <=>  inter > (0.4f - 2^-26)*denom in f64
//   (26x24-bit mantissa product is exact; midpoint ties round-to-even to
//   prev(0.4f) < 0.4f -> false, matching strict '>'). denom==0 => inter==0
//   => false, matching 0/0=NaN >= 0.4 false. Zero-padded boxes => false.
//
// Fused tail (former k_acon): lane t already holds adjacency word t of its
// rows -> iterate set bits, gather con[j][0..15], fmax-accumulate; 6-step
// shuffle max-reduce; thr[i][c] = max(adj_con, con_i) (exact: p>=a && p>=b
// <=> p >= fmax(a,b) for non-NaN inputs; adj_con init 0 matches reference
// where(adj, con, 0) and subsumes p>=0). Saves a dispatch + the 6.6 MB adj
// re-read the standalone kernel paid.
// ---------------------------------------------------------------------------
__global__ __launch_bounds__(256, 4) void k_adj(const float* __restrict__ boxes,
                                                const float* __restrict__ con,
                                                u64* __restrict__ adj,
                                                float* __restrict__ thr) {
#pragma clang fp contract(off)
    __shared__ float4 sbox[HW0_];    // (x1,y1,x2,y2), one j-half at a time
    const int tid  = threadIdx.x;
    const int lane = tid & 63;
    const int wv   = tid >> 6;
    const int g    = blockIdx.x;                 // 0 .. B*N/16-1
    const int b    = g / (N_ / RPB_);
    const int r0   = (g % (N_ / RPB_)) * RPB_ + wv * RPW_;
    const size_t bN = (size_t)b * N_;

    float4 bi[RPW_];
    float  ai[RPW_];
#pragma unroll
    for (int r = 0; r < RPW_; ++r) {
        const float4 bx = reinterpret_cast<const float4*>(boxes)[bN + r0 + r];
        const float x1 = bx.x - bx.z * 0.5f;   // cx - w/2 (reference op order)
        const float y1 = bx.y - bx.w * 0.5f;
        const float x2 = x1 + bx.z;
        const float y2 = y1 + bx.w;
        bi[r] = make_float4(x1, y1, x2, y2);
        ai[r] = (x2 - x1) * (y2 - y1);
    }
    const double MID = (double)0.4f - 0x1p-26;   // exact

    u64 row[RPW_];
#pragma unroll
    for (int r = 0; r < RPW_; ++r) row[r] = 0ull;

    int jbase = 0;
    for (int h = 0; h < 2; ++h) {
        const int cnt = h ? HW1_ : HW0_;
        __syncthreads();                         // protect previous half's reads
        for (int jj = tid; jj < cnt; jj += 256) {
            const int j = jbase + jj;
            float x1 = 0.f, y1 = 0.f, x2 = 0.f, y2 = 0.f;
            if (j < N_) {
                const float4 bx = reinterpret_cast<const float4*>(boxes)[bN + j];
                x1 = bx.x - bx.z * 0.5f;
                y1 = bx.y - bx.w * 0.5f;
                x2 = x1 + bx.z;
                y2 = y1 + bx.w;
            }
            sbox[jj] = make_float4(x1, y1, x2, y2);
        }
        __syncthreads();

        const int twn = cnt >> 6;
        for (int tw = 0; tw < twn; ++tw) {
            const int tglob = (jbase >> 6) + tw;
            const int j     = jbase + tw * 64 + lane;
            const float4 bj = sbox[tw * 64 + lane];
            const float ajr = (bj.z - bj.x) * (bj.w - bj.y);
#pragma unroll
            for (int r = 0; r < RPW_; ++r) {
                const float ltx = fmaxf(bi[r].x, bj.x);
                const float lty = fmaxf(bi[r].y, bj.y);
                const float rbx = fminf(bi[r].z, bj.z);
                const float rby = fminf(bi[r].w, bj.w);
                const float whx = fmaxf(rbx - ltx, 0.0f);
                const float why = fmaxf(rby - lty, 0.0f);
                const float inter = whx * why;
                const float denom = (ai[r] + ajr) - inter;
                const int pred = ((double)inter > MID * (double)denom) && (j != r0 + r);
                const u64 m = __ballot(pred);
                if (lane == tglob) row[r] = m;   // 2x v_cndmask
            }
        }
        jbase += cnt;
    }

#pragma unroll
    for (int r = 0; r < RPW_; ++r)
        if (lane < NW_) adj[(bN + r0 + r) * (size_t)NW_ + lane] = row[r];

    // ---- fused k_acon tail: rows are still live in registers ----
#pragma unroll 1
    for (int r = 0; r < RPW_; ++r) {
        const int i = r0 + r;
        u64 w = row[r];                          // lane t == word t; 0 for t>=NW_
        float cm[C_];
#pragma unroll
        for (int k = 0; k < C_; ++k) cm[k] = 0.0f;

        while (w) {
            const int bit = __builtin_ctzll(w); w &= w - 1;
            const int j   = lane * 64 + bit;
            const float4* cp = reinterpret_cast<const float4*>(con + (bN + j) * C_);
            const float4 c0 = cp[0], c1 = cp[1], c2 = cp[2], c3 = cp[3];
            cm[0]  = fmaxf(cm[0],  c0.x); cm[1]  = fmaxf(cm[1],  c0.y);
            cm[2]  = fmaxf(cm[2],  c0.z); cm[3]  = fmaxf(cm[3],  c0.w);
            cm[4]  = fmaxf(cm[4],  c1.x); cm[5]  = fmaxf(cm[5],  c1.y);
            cm[6]  = fmaxf(cm[6],  c1.z); cm[7]  = fmaxf(cm[7],  c1.w);
            cm[8]  = fmaxf(cm[8],  c2.x); cm[9]  = fmaxf(cm[9],  c2.y);
            cm[10] = fmaxf(cm[10], c2.z); cm[11] = fmaxf(cm[11], c2.w);
            cm[12] = fmaxf(cm[12], c3.x); cm[13] = fmaxf(cm[13], c3.y);
            cm[14] = fmaxf(cm[14], c3.z); cm[15] = fmaxf(cm[15], c3.w);
        }

#pragma unroll
        for (int off = 1; off < 64; off <<= 1) {
#pragma unroll
            for (int k = 0; k < C_; ++k) cm[k] = fmaxf(cm[k], __shfl_xor(cm[k], off));
        }
        if (lane == 0) {
            const float4* cp = reinterpret_cast<const float4*>(con + (bN + i) * C_);
            const float4 c0 = cp[0], c1 = cp[1], c2 = cp[2], c3 = cp[3];
            float4* o = reinterpret_cast<float4*>(thr + (bN + i) * C_);
            o[0] = make_float4(fmaxf(cm[0],  c0.x), fmaxf(cm[1],  c0.y),
                               fmaxf(cm[2],  c0.z), fmaxf(cm[3],  c0.w));
            o[1] = make_float4(fmaxf(cm[4],  c1.x), fmaxf(cm[5],  c1.y),
                               fmaxf(cm[6],  c1.z), fmaxf(cm[7],  c1.w));
            o[2] = make_float4(fmaxf(cm[8],  c2.x), fmaxf(cm[9],  c2.y),
                               fmaxf(cm[10], c2.z), fmaxf(cm[11], c2.w));
            o[3] = make_float4(fmaxf(cm[12], c3.x), fmaxf(cm[13], c3.y),
                               fmaxf(cm[14], c3.z), fmaxf(cm[15], c3.w));
        }
    }
}

// ---------------------------------------------------------------------------
// K2 (prep + sort + greedy + output): one 512-thread block per (b,c).
//  Phase 0: valid0 + vmask ballots (straight into LDS) + compaction into
//           64-bit keys ((~score_bits << 32) | idx).
//  Phase 1: RANK SORT (keys unique -> rank is a permutation): one pass over
//           keys per 512-element slot (T~330 -> 1 pass, 2 barriers total,
//           replacing the 45-barrier bitonic network). LDS reads broadcast.
//  Phase 2: chunk-parallel greedy (unchanged). keys[] is dead after sort,
//           so srows overlays it (union) — LDS unchanged.
//  Phase 3: full-slice output write incl. zeros (absorbs the memset node).
// Exactness: candidate accepted iff valid at its turn under prior chunks'
// suppressions (vmask) and earlier accepted rows in-chunk (intra) — the
// reference greedy restricted to valid0 members. Survivor order == greedy
// order == reference output order; suppressed rows written as exact zeros.
// ---------------------------------------------------------------------------
union OvT {
    u64 keys[NPAD_];                // 29.2 KB (live: phase 0/1)
    u64 srows[2][CH_][NW_];         // 58.4 KB (live: phase 2)
};

__global__ __launch_bounds__(NT_) void k_nms(const float* __restrict__ pro,
                                             const float* __restrict__ thr,
                                             const float* __restrict__ conf,
                                             const u64* __restrict__ adj,
                                             const float* __restrict__ boxes,
                                             const float* __restrict__ scales,
                                             float* __restrict__ out) {
#pragma clang fp contract(off)
    __shared__ OvT ov;
    __shared__ u32 sidx[NPAD_];
    __shared__ u64 sintra[CH_];
    __shared__ u64 vmask[NW_];
    __shared__ u64 s_accept;
    __shared__ u32 slist[NPAD_];
    __shared__ u32 s_T;
    __shared__ u32 s_S;
    const int tid  = threadIdx.x;
    const int lane = tid & 63;
    const int wv   = tid >> 6;
    const int bc   = blockIdx.x;
    const int b    = bc / C_, c = bc % C_;
    const size_t bN = (size_t)b * N_;
    const float cf = conf[c];

    if (tid == 0) s_T = 0;
    __syncthreads();

    // --- phase 0: valid0 + vmask + compaction ---
    for (int t = wv; t < NW_; t += NWV_) {
        const int i = t * 64 + lane;
        int pred = 0;
        u32 pk = 0;
        if (i < N_) {
            const size_t off = (bN + i) * C_ + c;
            const float p = pro[off];
            pred = (p >= cf) && (p >= thr[off]);
            const u32 pb = __float_as_uint(p);
            pk = pb ^ ((pb >> 31) ? 0xFFFFFFFFu : 0x80000000u);
        }
        const u64 bm = __ballot(pred);
        if (lane == 0) vmask[t] = bm;
        u32 base = 0;
        if (lane == 0 && bm) base = atomicAdd(&s_T, (u32)__popcll(bm));
        base = (u32)__shfl((int)base, 0);
        if (pred) ov.keys[base + (u32)__popcll(bm & ((1ull << lane) - 1ull))] =
            (((u64)(~pk)) << 32) | (u32)i;
    }
    __syncthreads();

    // --- phase 1: rank sort (asc; keys unique -> rank is a permutation) ---
    const int T = (int)s_T;
    for (int k = 0; k * NT_ < T; ++k) {          // one pass when T <= 512
        const int x  = tid + k * NT_;
        const u64 kx = (x < T) ? ov.keys[x] : ~0ull;
        u32 rank = 0;
        for (int y = 0; y < T; ++y) rank += (ov.keys[y] < kx);   // broadcast
        if (x < T) sidx[rank] = (u32)(kx & 0xFFFFFFFFull);
    }
    __syncthreads();                     // keys dead; srows may overlay now

    // --- phase 2: chunk-parallel greedy ---
    // stage chunk 0
#pragma unroll
    for (int rr = 0; rr < RPWG_; ++rr) {
        const int r = wv * RPWG_ + rr;
        const u32 idx = (r < T) ? sidx[r] : 0u;
        if (lane < NW_) ov.srows[0][r][lane] = adj[(bN + idx) * (size_t)NW_ + lane];
    }
    __syncthreads();

    u32 S = 0;                           // meaningful in wave 0
    const int NCH = (T + CH_ - 1) / CH_;
    for (int ch = 0; ch < NCH; ++ch) {
        const int cur = ch & 1, nxt = cur ^ 1;
        const int c0 = ch * CH_;
        const int cn = min(CH_, T - c0);
        const int havenext = (ch + 1 < NCH);

        // --- A: prefetch next chunk rows + intra-chunk masks (symmetry) ---
        u64 pre[RPWG_];
#pragma unroll
        for (int rr = 0; rr < RPWG_; ++rr) {
            const int r = wv * RPWG_ + rr;
            const int q = c0 + CH_ + r;
            const u32 idxn = (havenext && q < T) ? sidx[q] : 0u;
            pre[rr] = (havenext && lane < NW_)
                        ? adj[(bN + idxn) * (size_t)NW_ + lane] : 0ull;
        }
#pragma unroll
        for (int rr = 0; rr < RPWG_; ++rr) {
            const int r = wv * RPWG_ + rr;
            const u32 idxr = (c0 + r < T) ? sidx[c0 + r] : 0u;   // uniform/iter
            const u64 rj = ov.srows[cur][lane][idxr >> 6];  // own row, sym.
            const u64 ib = __ballot((lane < cn) && ((rj >> (idxr & 63)) & 1ull));
            if (lane == 0) sintra[r] = ib;
        }
        __syncthreads();

        // --- B: wave 0 sparse resolve + survivor emit ---
        if (wv == 0) {
            const u32 idxme = (c0 + lane < T) ? sidx[c0 + lane] : 0u;
            const u64 vm = vmask[idxme >> 6];            // LDS scatter read
            u64 cv = __ballot((lane < cn) && ((vm >> (idxme & 63)) & 1ull));
            const u64 iv = sintra[lane];
            const u32 ivLo = (u32)iv, ivHi = (u32)(iv >> 32);
            u64 accept = 0ull;
            while (cv) {
                const int r = __builtin_ctzll(cv);
                accept |= 1ull << r;
                const u64 ir =
                    ((u64)(u32)__builtin_amdgcn_readlane((int)ivHi, r) << 32)
                  |  (u64)(u32)__builtin_amdgcn_readlane((int)ivLo, r);
                cv &= ~(ir | (1ull << r));
            }
            if (lane == 0) s_accept = accept;
            const u32 bitl = (u32)((accept >> lane) & 1ull);
            if (bitl) {
                const u32 pos = S + (u32)__popcll(accept & ((1ull << lane) - 1ull));
                slist[pos] = idxme;
            }
            S += (u32)__popcll(accept);
        }
        __syncthreads();

        // --- C: parallel apply + store prefetched rows ---
        const u64 ac = s_accept;
        u64 acc = 0ull;
#pragma unroll
        for (int rr = 0; rr < RPWG_; ++rr) {
            const int r = wv * RPWG_ + rr;
            if ((ac >> r) & 1ull)                        // wave-uniform branch
                acc |= ov.srows[cur][r][min(lane, NW_ - 1)];
        }
        if (lane < NW_ && acc)
            atomicAnd(&vmask[lane], ~acc);
        if (havenext) {
#pragma unroll
            for (int rr = 0; rr < RPWG_; ++rr) {
                const int r = wv * RPWG_ + rr;
                if (lane < NW_) ov.srows[nxt][r][lane] = pre[rr];
            }
        }
        __syncthreads();
    }
    if (wv == 0 && lane == 0) s_S = S;
    __syncthreads();

    // --- phase 3: full-slice output (zeros past Sf; absorbs the memset) ---
    const int Sf = (int)s_S;
    const float s = scales[b];
    for (int r = tid; r < N_; r += NT_) {
        float o0 = 0.f, o1 = 0.f, o2 = 0.f, o3 = 0.f, o4 = 0.f, mk = 0.f;
        if (r < Sf) {
            const int idx = (int)slist[r];
            const float4 bx = reinterpret_cast<const float4*>(boxes)[bN + idx];
            const float scx = bx.x * s, scy = bx.y * s;
            const float sw  = bx.z * s, sh  = bx.w * s;
            o0 = scx - 0.5f * sw;
            o1 = scy - 0.5f * sh;
            o2 = scx + 0.5f * sw;
            o3 = scy + 0.5f * sh;
            o4 = pro[(bN + idx) * C_ + c];
            mk = 1.0f;
        }
        float* o = out + ((size_t)bc * N_ + r) * 5;
        o[0] = o0; o[1] = o1; o[2] = o2; o[3] = o3; o[4] = o4;
        out[(size_t)B_ * C_ * N_ * 5 + (size_t)bc * N_ + r] = mk;
    }
}

// ---------------------------------------------------------------------------
extern "C" void kernel_launch(void* const* d_in, const int* in_sizes, int n_in,
                              void* d_out, int out_size, void* d_ws, size_t ws_size,
                              hipStream_t stream) {
    const float* pro    = (const float*)d_in[0];   // (B,N,C)
    const float* con    = (const float*)d_in[1];   // (B,N,C)
    const float* boxes  = (const float*)d_in[2];   // (B,N,4)
    const float* scales = (const float*)d_in[3];   // (B,)
    const float* conf   = (const float*)d_in[4];   // (C,)

    char* ws = (char*)d_ws;
    u64* adj = (u64*)ws;                                   // B*N*NW u64  (6.57 MB)
    size_t off = (size_t)B_ * N_ * NW_ * sizeof(u64);
    float* thr = (float*)(ws + off);                       // B*N*C f32   (0.92 MB)

    k_adj<<<B_ * N_ / RPB_, 256, 0, stream>>>(boxes, con, adj, thr);
    k_nms<<<B_ * C_,        NT_, 0, stream>>>(pro, thr, conf, adj, boxes,
                                              scales, (float*)d_out);
}